// Round 4
// baseline (613.969 us; speedup 1.0000x reference)
//
#include <hip/hip_runtime.h>

// Neural Additive Model: 256 per-feature MLPs 1->128->64->32->1 (ReLU), summed.
// B=8192, fp32. Compute-bound: 21.8 GMAC -> 278 us floor at scalar v_fma_f32
// rate (157 TF); ~150 us if v_pk_fma_f32 doubles FLOP/cycle.
//
// Round 4: round-3 still spilled (VGPR_Count=40 with 64 live acc floats ->
// G spilled around the j-loop; hidden from HBM counters by L2/L3).
//   * __launch_bounds__(256, 2): min 2 waves/EU -> allocator may use up to
//     256 VGPRs. Need ~120. No spill.
//   * single pass over all 64 h2 channels (A:64 + G:32 floats in VGPRs),
//     no duplicated layer-1 compute, j-loop runs once.
//   * #pragma unroll 2 on j-loop: body stays ~12 KB << 32 KB I$ (round-2 lesson).
// Weights wave-uniform -> s_load + VALU fma with SGPR src; 1 instr / 1-2 MACs.

typedef float fvec2 __attribute__((ext_vector_type(2)));

#define NF   256
#define NH1  128
#define NH2  64
#define NH3  32
#define NB   8192

__device__ __forceinline__ fvec2 ld2(const float* p) { return *(const fvec2*)p; }
__device__ __forceinline__ float relu(float v) { return fmaxf(v, 0.0f); }
__device__ __forceinline__ fvec2 relu2(fvec2 v) {
    fvec2 z = {0.0f, 0.0f};
    return __builtin_elementwise_max(v, z);
}
// c += a * b, forced FMA (scalar a broadcast into both lanes)
__device__ __forceinline__ fvec2 fma2s(float a, fvec2 b, fvec2 c) {
    fvec2 av; av.x = a; av.y = a;
    return __builtin_elementwise_fma(av, b, c);
}

__global__ __launch_bounds__(256) void init_out_kernel(float* __restrict__ out,
                                                       const float* __restrict__ bias) {
    int i = blockIdx.x * 256 + threadIdx.x;
    if (i < NB) out[i] = bias[0];
}

// Layer-2 accumulate for one j: A[0:64] += h1 * W2[j][0:64]
#define L2J(h1, w2r) { \
    A0  = fma2s(h1, ld2((w2r) +  0), A0);  A1  = fma2s(h1, ld2((w2r) +  2), A1);  \
    A2  = fma2s(h1, ld2((w2r) +  4), A2);  A3  = fma2s(h1, ld2((w2r) +  6), A3);  \
    A4  = fma2s(h1, ld2((w2r) +  8), A4);  A5  = fma2s(h1, ld2((w2r) + 10), A5);  \
    A6  = fma2s(h1, ld2((w2r) + 12), A6);  A7  = fma2s(h1, ld2((w2r) + 14), A7);  \
    A8  = fma2s(h1, ld2((w2r) + 16), A8);  A9  = fma2s(h1, ld2((w2r) + 18), A9);  \
    A10 = fma2s(h1, ld2((w2r) + 20), A10); A11 = fma2s(h1, ld2((w2r) + 22), A11); \
    A12 = fma2s(h1, ld2((w2r) + 24), A12); A13 = fma2s(h1, ld2((w2r) + 26), A13); \
    A14 = fma2s(h1, ld2((w2r) + 28), A14); A15 = fma2s(h1, ld2((w2r) + 30), A15); \
    A16 = fma2s(h1, ld2((w2r) + 32), A16); A17 = fma2s(h1, ld2((w2r) + 34), A17); \
    A18 = fma2s(h1, ld2((w2r) + 36), A18); A19 = fma2s(h1, ld2((w2r) + 38), A19); \
    A20 = fma2s(h1, ld2((w2r) + 40), A20); A21 = fma2s(h1, ld2((w2r) + 42), A21); \
    A22 = fma2s(h1, ld2((w2r) + 44), A22); A23 = fma2s(h1, ld2((w2r) + 46), A23); \
    A24 = fma2s(h1, ld2((w2r) + 48), A24); A25 = fma2s(h1, ld2((w2r) + 50), A25); \
    A26 = fma2s(h1, ld2((w2r) + 52), A26); A27 = fma2s(h1, ld2((w2r) + 54), A27); \
    A28 = fma2s(h1, ld2((w2r) + 56), A28); A29 = fma2s(h1, ld2((w2r) + 58), A29); \
    A30 = fma2s(h1, ld2((w2r) + 60), A30); A31 = fma2s(h1, ld2((w2r) + 62), A31); }

// One layer-3 row: G[0:32] += relu(h2val) * W3[krow][0:32]
#define L3ROW(val, krow) { \
    const float h2v = relu(val); \
    const float* w3r = w3 + (krow) * NH3; \
    G0  = fma2s(h2v, ld2(w3r +  0), G0);  G1  = fma2s(h2v, ld2(w3r +  2), G1);  \
    G2  = fma2s(h2v, ld2(w3r +  4), G2);  G3  = fma2s(h2v, ld2(w3r +  6), G3);  \
    G4  = fma2s(h2v, ld2(w3r +  8), G4);  G5  = fma2s(h2v, ld2(w3r + 10), G5);  \
    G6  = fma2s(h2v, ld2(w3r + 12), G6);  G7  = fma2s(h2v, ld2(w3r + 14), G7);  \
    G8  = fma2s(h2v, ld2(w3r + 16), G8);  G9  = fma2s(h2v, ld2(w3r + 18), G9);  \
    G10 = fma2s(h2v, ld2(w3r + 20), G10); G11 = fma2s(h2v, ld2(w3r + 22), G11); \
    G12 = fma2s(h2v, ld2(w3r + 24), G12); G13 = fma2s(h2v, ld2(w3r + 26), G13); \
    G14 = fma2s(h2v, ld2(w3r + 28), G14); G15 = fma2s(h2v, ld2(w3r + 30), G15); }

__global__ __launch_bounds__(256, 2) void nam_kernel(
    const float* __restrict__ x,
    const float* __restrict__ W1, const float* __restrict__ b1,
    const float* __restrict__ W2, const float* __restrict__ b2,
    const float* __restrict__ W3, const float* __restrict__ b3,
    const float* __restrict__ W4, const float* __restrict__ b4,
    float* __restrict__ out)
{
    // 32 consecutive blocks share one feature -> L2/L3 weight reuse.
    const int f  = blockIdx.x >> 5;            // feature (wave-uniform)
    const int bt = blockIdx.x & 31;            // batch tile
    const int b  = bt * 256 + (int)threadIdx.x;

    const float xv = x[b * NF + f];

    const float* __restrict__ w1  = W1 + f * NH1;
    const float* __restrict__ bb1 = b1 + f * NH1;
    const float* __restrict__ w2  = W2 + f * NH1 * NH2;
    const float* __restrict__ bb2 = b2 + f * NH2;
    const float* __restrict__ w3  = W3 + f * NH2 * NH3;
    const float* __restrict__ bb3 = b3 + f * NH3;
    const float* __restrict__ w4  = W4 + f * NH3;

    // h3 accumulators (32 floats), init with b3.
    fvec2 G0 = ld2(bb3 + 0),  G1 = ld2(bb3 + 2),  G2 = ld2(bb3 + 4),  G3 = ld2(bb3 + 6),
          G4 = ld2(bb3 + 8),  G5 = ld2(bb3 + 10), G6 = ld2(bb3 + 12), G7 = ld2(bb3 + 14),
          G8 = ld2(bb3 + 16), G9 = ld2(bb3 + 18), G10 = ld2(bb3 + 20), G11 = ld2(bb3 + 22),
          G12 = ld2(bb3 + 24), G13 = ld2(bb3 + 26), G14 = ld2(bb3 + 28), G15 = ld2(bb3 + 30);

    // h2 accumulators (64 floats), init with b2.
    fvec2 A0  = ld2(bb2 + 0),  A1  = ld2(bb2 + 2),  A2  = ld2(bb2 + 4),  A3  = ld2(bb2 + 6),
          A4  = ld2(bb2 + 8),  A5  = ld2(bb2 + 10), A6  = ld2(bb2 + 12), A7  = ld2(bb2 + 14),
          A8  = ld2(bb2 + 16), A9  = ld2(bb2 + 18), A10 = ld2(bb2 + 20), A11 = ld2(bb2 + 22),
          A12 = ld2(bb2 + 24), A13 = ld2(bb2 + 26), A14 = ld2(bb2 + 28), A15 = ld2(bb2 + 30),
          A16 = ld2(bb2 + 32), A17 = ld2(bb2 + 34), A18 = ld2(bb2 + 36), A19 = ld2(bb2 + 38),
          A20 = ld2(bb2 + 40), A21 = ld2(bb2 + 42), A22 = ld2(bb2 + 44), A23 = ld2(bb2 + 46),
          A24 = ld2(bb2 + 48), A25 = ld2(bb2 + 50), A26 = ld2(bb2 + 52), A27 = ld2(bb2 + 54),
          A28 = ld2(bb2 + 56), A29 = ld2(bb2 + 58), A30 = ld2(bb2 + 60), A31 = ld2(bb2 + 62);

    // layer 1 + 2: A[k] += relu(x*W1[j]+b1[j]) * W2[j][k], all 64 k at once.
    #pragma unroll 2
    for (int j = 0; j < NH1; ++j) {
        const float h1 = relu(fmaf(xv, w1[j], bb1[j]));
        const float* w2r = w2 + j * NH2;
        L2J(h1, w2r)
    }

    // layer 3: 64 rows, one code copy (~10 KB, fits I$).
    L3ROW(A0.x,  0)  L3ROW(A0.y,  1)  L3ROW(A1.x,  2)  L3ROW(A1.y,  3)
    L3ROW(A2.x,  4)  L3ROW(A2.y,  5)  L3ROW(A3.x,  6)  L3ROW(A3.y,  7)
    L3ROW(A4.x,  8)  L3ROW(A4.y,  9)  L3ROW(A5.x, 10)  L3ROW(A5.y, 11)
    L3ROW(A6.x, 12)  L3ROW(A6.y, 13)  L3ROW(A7.x, 14)  L3ROW(A7.y, 15)
    L3ROW(A8.x, 16)  L3ROW(A8.y, 17)  L3ROW(A9.x, 18)  L3ROW(A9.y, 19)
    L3ROW(A10.x, 20) L3ROW(A10.y, 21) L3ROW(A11.x, 22) L3ROW(A11.y, 23)
    L3ROW(A12.x, 24) L3ROW(A12.y, 25) L3ROW(A13.x, 26) L3ROW(A13.y, 27)
    L3ROW(A14.x, 28) L3ROW(A14.y, 29) L3ROW(A15.x, 30) L3ROW(A15.y, 31)
    L3ROW(A16.x, 32) L3ROW(A16.y, 33) L3ROW(A17.x, 34) L3ROW(A17.y, 35)
    L3ROW(A18.x, 36) L3ROW(A18.y, 37) L3ROW(A19.x, 38) L3ROW(A19.y, 39)
    L3ROW(A20.x, 40) L3ROW(A20.y, 41) L3ROW(A21.x, 42) L3ROW(A21.y, 43)
    L3ROW(A22.x, 44) L3ROW(A22.y, 45) L3ROW(A23.x, 46) L3ROW(A23.y, 47)
    L3ROW(A24.x, 48) L3ROW(A24.y, 49) L3ROW(A25.x, 50) L3ROW(A25.y, 51)
    L3ROW(A26.x, 52) L3ROW(A26.y, 53) L3ROW(A27.x, 54) L3ROW(A27.y, 55)
    L3ROW(A28.x, 56) L3ROW(A28.y, 57) L3ROW(A29.x, 58) L3ROW(A29.y, 59)
    L3ROW(A30.x, 60) L3ROW(A30.y, 61) L3ROW(A31.x, 62) L3ROW(A31.y, 63)

    // layer 4: o = b4[f] + sum_m relu(h3[m]) * W4[m]
    fvec2 OV = {0.0f, 0.0f};
    #define L4(Gi, off) OV = __builtin_elementwise_fma(relu2(Gi), ld2(w4 + (off)), OV);
    L4(G0, 0)   L4(G1, 2)   L4(G2, 4)   L4(G3, 6)
    L4(G4, 8)   L4(G5, 10)  L4(G6, 12)  L4(G7, 14)
    L4(G8, 16)  L4(G9, 18)  L4(G10, 20) L4(G11, 22)
    L4(G12, 24) L4(G13, 26) L4(G14, 28) L4(G15, 30)
    #undef L4
    const float o = b4[f] + (OV.x + OV.y);

    atomicAdd(&out[b], o);
}

extern "C" void kernel_launch(void* const* d_in, const int* in_sizes, int n_in,
                              void* d_out, int out_size, void* d_ws, size_t ws_size,
                              hipStream_t stream) {
    const float* x    = (const float*)d_in[0];
    const float* W1   = (const float*)d_in[1];
    const float* b1   = (const float*)d_in[2];
    const float* W2   = (const float*)d_in[3];
    const float* b2   = (const float*)d_in[4];
    const float* W3   = (const float*)d_in[5];
    const float* b3   = (const float*)d_in[6];
    const float* W4   = (const float*)d_in[7];
    const float* b4   = (const float*)d_in[8];
    const float* bias = (const float*)d_in[9];
    float* out = (float*)d_out;

    // d_out is poisoned (0xAA) before every launch: initialize to bias.
    init_out_kernel<<<NB / 256, 256, 0, stream>>>(out, bias);

    nam_kernel<<<NF * (NB / 256), 256, 0, stream>>>(
        x, W1, b1, W2, b2, W3, b3, W4, b4, out);
}

// Round 5
// 241.247 us; speedup vs baseline: 2.5450x; 2.5450x over previous
//
#include <hip/hip_runtime.h>
#include <math.h>

// Neural Additive Model: 256 per-feature MLPs 1->128->64->32->1 (ReLU), summed.
// B=8192, fp32.
//
// Round 5: ALGORITHMIC change. h1_j = relu(x*w1_j + b1_j) is a function of the
// SCALAR x: unit j is active iff x is past threshold t_j = -b1_j/w1_j
// (above for w1_j>0, below for w1_j<0). Therefore
//   h2[b,k] = x_b * S_w[rank(x_b),k] + S_b[rank(x_b),k]
// with rank = #(sorted thresholds < x) and S_w/S_b prefix-sum tables built by
// sorting thresholds and toggling (+w1_j*W2[j,:]) / (-...) per crossing.
// This deletes layer 2's 17.2 GMAC (79% of total) EXACTLY, in fp32.
// Remaining hot loop: layer 3 (4.3 GMAC -> ~55 us VALU floor).
//
//   build_tables: 1 block/feature: bitonic-sort 128 thresholds, scan -> d_ws
//                 tables S[129][64] of float2(Sw,Sb) + sorted T[128].
//   nam_main:     1 block = (feature, 512 batch rows). Stage table into LDS
//                 (67.6 KB static; gfx950 LDS = 160 KB, 2 blocks/CU),
//                 binary-search r (7 LDS reads), then layer 3 with G[32]
//                 accumulators only (fits 128-VGPR budget, no spill).
// Table rows padded to 65 float2 -> divergent-r LDS gathers spread banks.

typedef float fvec2 __attribute__((ext_vector_type(2)));

#define NF   256
#define NH1  128
#define NH2  64
#define NH3  32
#define NB   8192

// floats per feature in ws: T[128] + S[129][64] float2 pairs
#define FSTRIDE (NH1 + 129 * NH2 * 2)

__device__ __forceinline__ fvec2 ld2(const float* p) { return *(const fvec2*)p; }
__device__ __forceinline__ fvec2 relu2(fvec2 v) {
    fvec2 z = {0.0f, 0.0f};
    return __builtin_elementwise_max(v, z);
}
__device__ __forceinline__ fvec2 fma2s(float a, fvec2 b, fvec2 c) {
    fvec2 av; av.x = a; av.y = a;
    return __builtin_elementwise_fma(av, b, c);
}

__global__ __launch_bounds__(256) void init_out_kernel(float* __restrict__ out,
                                                       const float* __restrict__ bias) {
    int i = blockIdx.x * 256 + threadIdx.x;
    if (i < NB) out[i] = bias[0];
}

// ---------------- table build: one block (64 threads) per feature ----------------
__global__ __launch_bounds__(64) void build_tables(
    const float* __restrict__ W1, const float* __restrict__ b1,
    const float* __restrict__ W2, const float* __restrict__ b2,
    float* __restrict__ ws)
{
    __shared__ float w2s[NH1 * NH2];   // 32 KB: W2[f] staged
    __shared__ float tkey[NH1];
    __shared__ int   tidx[NH1];
    __shared__ float w1s[NH1], b1s[NH1];

    const int f = blockIdx.x;
    const int t = threadIdx.x;

    // stage W2[f] (32 KB) into LDS, float4-coalesced
    {
        const float4* w2g = (const float4*)(W2 + (size_t)f * NH1 * NH2);
        float4* w2l = (float4*)w2s;
        #pragma unroll 4
        for (int i = t; i < NH1 * NH2 / 4; i += 64) w2l[i] = w2g[i];
    }
    for (int i = t; i < NH1; i += 64) {
        float w  = W1[f * NH1 + i];
        float bb = b1[f * NH1 + i];
        w1s[i] = w; b1s[i] = bb;
        tkey[i] = (w != 0.0f) ? (-bb / w) : INFINITY;  // w==0: never toggled
        tidx[i] = i;
    }
    __syncthreads();

    // bitonic sort of 128 (key tkey asc, payload tidx); 64 threads = 64 pairs/stage
    for (int size = 2; size <= NH1; size <<= 1) {
        for (int stride = size >> 1; stride > 0; stride >>= 1) {
            int pos = ((t / stride) * (stride << 1)) + (t % stride);
            int par = pos + stride;
            bool up = ((pos & size) == 0);
            float a = tkey[pos], c = tkey[par];
            int  ia = tidx[pos], ic = tidx[par];
            if ((a > c) == up) {
                tkey[pos] = c; tkey[par] = a;
                tidx[pos] = ic; tidx[par] = ia;
            }
            __syncthreads();
        }
    }

    // scan: thread t owns h2 column k = t.
    const int k = t;
    float accw = 0.0f;
    float accb = b2[f * NH2 + k];
    // rank 0 state (x below all thresholds): all w<0 units active,
    // plus w==0 units contribute constant relu(b1)=b1 if b1>0.
    for (int j = 0; j < NH1; ++j) {
        float w = w1s[j], bb = b1s[j];
        float w2v = w2s[j * NH2 + k];
        if (w < 0.0f)       { accw = fmaf(w,  w2v, accw); accb = fmaf(bb, w2v, accb); }
        else if (w == 0.0f && bb > 0.0f) { accb = fmaf(bb, w2v, accb); }
    }
    float2* Sg = (float2*)(ws + (size_t)f * FSTRIDE + NH1);
    { float2 v; v.x = accw; v.y = accb; Sg[k] = v; }
    // crossing threshold r-1 (ascending): w>0 activates (+), w<0 deactivates (-)
    #pragma unroll 2
    for (int r = 1; r <= NH1; ++r) {
        int j = tidx[r - 1];                 // wave-uniform broadcast
        float w = w1s[j], bb = b1s[j];
        float w2v = w2s[j * NH2 + k];
        float s = (w > 0.0f) ? 1.0f : ((w < 0.0f) ? -1.0f : 0.0f);
        accw = fmaf(s * w,  w2v, accw);
        accb = fmaf(s * bb, w2v, accb);
        float2 v; v.x = accw; v.y = accb;
        Sg[r * NH2 + k] = v;
    }
    // sorted thresholds out
    for (int i = t; i < NH1; i += 64) ws[(size_t)f * FSTRIDE + i] = tkey[i];
}

// ---------------- main: one block = (feature, 512 batch rows) ----------------
__global__ __launch_bounds__(512, 4) void nam_main(
    const float* __restrict__ x,
    const float* __restrict__ W3, const float* __restrict__ b3,
    const float* __restrict__ W4, const float* __restrict__ b4,
    const float* __restrict__ ws,
    float* __restrict__ out)
{
    __shared__ float2 S[129 * 65];   // row stride 65 (pad) -> bank spread; 67.1 KB
    __shared__ float  Tl[NH1];       // sorted thresholds

    const int f    = blockIdx.x >> 4;          // feature (wave-uniform)
    const int tile = blockIdx.x & 15;
    const int t    = (int)threadIdx.x;
    const int b    = tile * 512 + t;

    // stage table (129x64 float2) global -> LDS with re-pad to stride 65
    {
        const float2* Sg = (const float2*)(ws + (size_t)f * FSTRIDE + NH1);
        #pragma unroll 4
        for (int i = t; i < 129 * NH2; i += 512) {
            int r = i >> 6, k = i & 63;
            S[r * 65 + k] = Sg[i];
        }
        if (t < NH1) Tl[t] = ws[(size_t)f * FSTRIDE + t];
    }
    __syncthreads();

    const float xv = x[b * NF + f];

    // rank = #(T < xv), branchless binary search over 128 sorted keys
    int r = 0;
    #pragma unroll
    for (int s = 64; s > 0; s >>= 1)
        if (Tl[r + s - 1] < xv) r += s;

    const float* __restrict__ w3  = W3 + f * NH2 * NH3;
    const float* __restrict__ bb3 = b3 + f * NH3;
    const float* __restrict__ w4  = W4 + f * NH3;

    // h3 accumulators (32 floats), init b3
    fvec2 G0 = ld2(bb3 + 0),  G1 = ld2(bb3 + 2),  G2 = ld2(bb3 + 4),  G3 = ld2(bb3 + 6),
          G4 = ld2(bb3 + 8),  G5 = ld2(bb3 + 10), G6 = ld2(bb3 + 12), G7 = ld2(bb3 + 14),
          G8 = ld2(bb3 + 16), G9 = ld2(bb3 + 18), G10 = ld2(bb3 + 20), G11 = ld2(bb3 + 22),
          G12 = ld2(bb3 + 24), G13 = ld2(bb3 + 26), G14 = ld2(bb3 + 28), G15 = ld2(bb3 + 30);

    // layer "2"(table) + 3: h2_k = relu(x*Sw + Sb); G += h2_k * W3[k,:]
    const float2* Srow = S + r * 65;
    #pragma unroll 2
    for (int k = 0; k < NH2; ++k) {
        float2 sv = Srow[k];                       // ds_read_b64, divergent r
        float h2 = fmaxf(fmaf(xv, sv.x, sv.y), 0.0f);
        const float* w3r = w3 + k * NH3;           // wave-uniform -> s_load
        G0  = fma2s(h2, ld2(w3r +  0), G0);  G1  = fma2s(h2, ld2(w3r +  2), G1);
        G2  = fma2s(h2, ld2(w3r +  4), G2);  G3  = fma2s(h2, ld2(w3r +  6), G3);
        G4  = fma2s(h2, ld2(w3r +  8), G4);  G5  = fma2s(h2, ld2(w3r + 10), G5);
        G6  = fma2s(h2, ld2(w3r + 12), G6);  G7  = fma2s(h2, ld2(w3r + 14), G7);
        G8  = fma2s(h2, ld2(w3r + 16), G8);  G9  = fma2s(h2, ld2(w3r + 18), G9);
        G10 = fma2s(h2, ld2(w3r + 20), G10); G11 = fma2s(h2, ld2(w3r + 22), G11);
        G12 = fma2s(h2, ld2(w3r + 24), G12); G13 = fma2s(h2, ld2(w3r + 26), G13);
        G14 = fma2s(h2, ld2(w3r + 28), G14); G15 = fma2s(h2, ld2(w3r + 30), G15);
    }

    // layer 4
    fvec2 OV = {0.0f, 0.0f};
    OV = __builtin_elementwise_fma(relu2(G0),  ld2(w4 + 0),  OV);
    OV = __builtin_elementwise_fma(relu2(G1),  ld2(w4 + 2),  OV);
    OV = __builtin_elementwise_fma(relu2(G2),  ld2(w4 + 4),  OV);
    OV = __builtin_elementwise_fma(relu2(G3),  ld2(w4 + 6),  OV);
    OV = __builtin_elementwise_fma(relu2(G4),  ld2(w4 + 8),  OV);
    OV = __builtin_elementwise_fma(relu2(G5),  ld2(w4 + 10), OV);
    OV = __builtin_elementwise_fma(relu2(G6),  ld2(w4 + 12), OV);
    OV = __builtin_elementwise_fma(relu2(G7),  ld2(w4 + 14), OV);
    OV = __builtin_elementwise_fma(relu2(G8),  ld2(w4 + 16), OV);
    OV = __builtin_elementwise_fma(relu2(G9),  ld2(w4 + 18), OV);
    OV = __builtin_elementwise_fma(relu2(G10), ld2(w4 + 20), OV);
    OV = __builtin_elementwise_fma(relu2(G11), ld2(w4 + 22), OV);
    OV = __builtin_elementwise_fma(relu2(G12), ld2(w4 + 24), OV);
    OV = __builtin_elementwise_fma(relu2(G13), ld2(w4 + 26), OV);
    OV = __builtin_elementwise_fma(relu2(G14), ld2(w4 + 28), OV);
    OV = __builtin_elementwise_fma(relu2(G15), ld2(w4 + 30), OV);
    const float o = b4[f] + (OV.x + OV.y);

    atomicAdd(&out[b], o);
}

extern "C" void kernel_launch(void* const* d_in, const int* in_sizes, int n_in,
                              void* d_out, int out_size, void* d_ws, size_t ws_size,
                              hipStream_t stream) {
    const float* x    = (const float*)d_in[0];
    const float* W1   = (const float*)d_in[1];
    const float* b1   = (const float*)d_in[2];
    const float* W2   = (const float*)d_in[3];
    const float* b2   = (const float*)d_in[4];
    const float* W3   = (const float*)d_in[5];
    const float* b3   = (const float*)d_in[6];
    const float* W4   = (const float*)d_in[7];
    const float* b4   = (const float*)d_in[8];
    const float* bias = (const float*)d_in[9];
    float* out = (float*)d_out;
    float* ws  = (float*)d_ws;   // needs 256*FSTRIDE*4 = 17.0 MB

    init_out_kernel<<<NB / 256, 256, 0, stream>>>(out, bias);
    build_tables<<<NF, 64, 0, stream>>>(W1, b1, W2, b2, ws);
    nam_main<<<NF * (NB / 512), 512, 0, stream>>>(x, W3, b3, W4, b4, ws, out);
}

// Round 6
// 209.849 us; speedup vs baseline: 2.9258x; 1.1496x over previous
//
#include <hip/hip_runtime.h>
#include <math.h>

// Neural Additive Model: 256 per-feature MLPs 1->128->64->32->1 (ReLU), summed.
// B=8192, fp32.
//
// Structure (round 5, exact): h1-layer collapses to a rank lookup:
//   pre-relu h2[b,k] = x_b * Sw[rank(x_b),k] + Sb[rank(x_b),k]
// (rank = #(sorted layer-1 thresholds < x)). Layers 2-relu/3/4 explicit.
//
// Round 6 fixes (from rocprof):
//  * 1.42e7 LDS bank-conflict cycles: table was rank-major float2 -> divergent
//    rank index had stride 130 floats -> 16-bank footprint, 4-way conflicts.
//    Fix: k-major scalar arrays Sw[k][132], Sb[k][132] -> divergent r has
//    coefficient 1 -> full 32-bank spread, ~2-way = free.
//  * Occupancy capped 41% (68KB LDS, 512-thr blocks -> 16 waves/CU).
//    Fix: 1024-thr blocks, 2 elems/thread -> 2 blocks/CU = 32 waves/CU.

typedef float fvec2 __attribute__((ext_vector_type(2)));

#define NF   256
#define NH1  128
#define NH2  64
#define NH3  32
#define NB   8192

#define SPAD 132                       // k-row stride (float4-copyable, r coeff 1)
#define SHALF (NH2 * SPAD)             // 8448 floats per array
// floats per feature in ws: T[128] + Sw[64*132] + Sb[64*132]
#define FSTRIDE (NH1 + 2 * SHALF)      // 17024 floats -> 17.4 MB total

__device__ __forceinline__ fvec2 ld2(const float* p) { return *(const fvec2*)p; }
__device__ __forceinline__ fvec2 relu2(fvec2 v) {
    fvec2 z = {0.0f, 0.0f};
    return __builtin_elementwise_max(v, z);
}
__device__ __forceinline__ fvec2 fma2s(float a, fvec2 b, fvec2 c) {
    fvec2 av; av.x = a; av.y = a;
    return __builtin_elementwise_fma(av, b, c);
}

__global__ __launch_bounds__(256) void init_out_kernel(float* __restrict__ out,
                                                       const float* __restrict__ bias) {
    int i = blockIdx.x * 256 + threadIdx.x;
    if (i < NB) out[i] = bias[0];
}

// ---------------- table build: one block (64 threads) per feature ----------------
__global__ __launch_bounds__(64) void build_tables(
    const float* __restrict__ W1, const float* __restrict__ b1,
    const float* __restrict__ W2, const float* __restrict__ b2,
    float* __restrict__ ws)
{
    __shared__ float w2s[NH1 * NH2];   // 32 KB: W2[f] staged
    __shared__ float tkey[NH1];
    __shared__ int   tidx[NH1];
    __shared__ float w1s[NH1], b1s[NH1];

    const int f = blockIdx.x;
    const int t = threadIdx.x;

    {
        const float4* w2g = (const float4*)(W2 + (size_t)f * NH1 * NH2);
        float4* w2l = (float4*)w2s;
        #pragma unroll 4
        for (int i = t; i < NH1 * NH2 / 4; i += 64) w2l[i] = w2g[i];
    }
    for (int i = t; i < NH1; i += 64) {
        float w  = W1[f * NH1 + i];
        float bb = b1[f * NH1 + i];
        w1s[i] = w; b1s[i] = bb;
        tkey[i] = (w != 0.0f) ? (-bb / w) : INFINITY;  // w==0: never toggled
        tidx[i] = i;
    }
    __syncthreads();

    // bitonic sort of 128 (key asc, payload idx); 64 threads = 64 pairs/stage
    for (int size = 2; size <= NH1; size <<= 1) {
        for (int stride = size >> 1; stride > 0; stride >>= 1) {
            int pos = ((t / stride) * (stride << 1)) + (t % stride);
            int par = pos + stride;
            bool up = ((pos & size) == 0);
            float a = tkey[pos], c = tkey[par];
            int  ia = tidx[pos], ic = tidx[par];
            if ((a > c) == up) {
                tkey[pos] = c; tkey[par] = a;
                tidx[pos] = ic; tidx[par] = ia;
            }
            __syncthreads();
        }
    }

    // scan: thread t owns h2 column k = t. Store k-major: ws[...+k*132+r].
    const int k = t;
    float* Swg = ws + (size_t)f * FSTRIDE + NH1 + k * SPAD;
    float* Sbg = Swg + SHALF;
    float accw = 0.0f;
    float accb = b2[f * NH2 + k];
    // rank 0 (x below all thresholds): w<0 units active; w==0,b1>0 constant-on.
    for (int j = 0; j < NH1; ++j) {
        float w = w1s[j], bb = b1s[j];
        float w2v = w2s[j * NH2 + k];
        if (w < 0.0f)       { accw = fmaf(w,  w2v, accw); accb = fmaf(bb, w2v, accb); }
        else if (w == 0.0f && bb > 0.0f) { accb = fmaf(bb, w2v, accb); }
    }
    Swg[0] = accw; Sbg[0] = accb;
    // crossing threshold r-1 (ascending): w>0 activates (+), w<0 deactivates (-)
    #pragma unroll 2
    for (int r = 1; r <= NH1; ++r) {
        int j = tidx[r - 1];                 // wave-uniform broadcast
        float w = w1s[j], bb = b1s[j];
        float w2v = w2s[j * NH2 + k];
        float s = (w > 0.0f) ? 1.0f : ((w < 0.0f) ? -1.0f : 0.0f);
        accw = fmaf(s * w,  w2v, accw);
        accb = fmaf(s * bb, w2v, accb);
        Swg[r] = accw; Sbg[r] = accb;
    }
    for (int i = t; i < NH1; i += 64) ws[(size_t)f * FSTRIDE + i] = tkey[i];
}

// ---------------- main: one block = (feature, 2048 batch rows) ----------------
__global__ __launch_bounds__(1024, 2) void nam_main(
    const float* __restrict__ x,
    const float* __restrict__ W3, const float* __restrict__ b3,
    const float* __restrict__ W4, const float* __restrict__ b4,
    const float* __restrict__ ws,
    float* __restrict__ out)
{
    __shared__ float Sl[2 * SHALF];   // Sw then Sb, k-major stride 132; 66 KB
    __shared__ float Tl[NH1];

    const int f    = blockIdx.x >> 2;          // feature (wave-uniform)
    const int tile = blockIdx.x & 3;
    const int t    = (int)threadIdx.x;

    // stage table: flat float4 copy (global layout == LDS layout)
    {
        const float* wsF = ws + (size_t)f * FSTRIDE;
        const float4* src = (const float4*)(wsF + NH1);
        float4* dst = (float4*)Sl;
        #pragma unroll 4
        for (int i = t; i < 2 * SHALF / 4; i += 1024) dst[i] = src[i];
        if (t < NH1) Tl[t] = wsF[t];
    }
    __syncthreads();

    const float* __restrict__ w3  = W3 + f * NH2 * NH3;
    const float* __restrict__ bb3 = b3 + f * NH3;
    const float* __restrict__ w4  = W4 + f * NH3;
    const float b4f = b4[f];

    // two batch elements per thread, processed sequentially (G regs reused)
    #pragma unroll 1
    for (int e = 0; e < 2; ++e) {
        const int b = tile * 2048 + e * 1024 + t;
        const float xv = x[b * NF + f];

        // rank = #(T < xv), branchless binary search
        int r = 0;
        #pragma unroll
        for (int s = 64; s > 0; s >>= 1)
            if (Tl[r + s - 1] < xv) r += s;

        // h3 accumulators (32 floats), init b3
        fvec2 G0 = ld2(bb3 + 0),  G1 = ld2(bb3 + 2),  G2 = ld2(bb3 + 4),  G3 = ld2(bb3 + 6),
              G4 = ld2(bb3 + 8),  G5 = ld2(bb3 + 10), G6 = ld2(bb3 + 12), G7 = ld2(bb3 + 14),
              G8 = ld2(bb3 + 16), G9 = ld2(bb3 + 18), G10 = ld2(bb3 + 20), G11 = ld2(bb3 + 22),
              G12 = ld2(bb3 + 24), G13 = ld2(bb3 + 26), G14 = ld2(bb3 + 28), G15 = ld2(bb3 + 30);

        // layer 2(table)+relu, then layer 3
        #pragma unroll 2
        for (int k = 0; k < NH2; ++k) {
            const float sw = Sl[k * SPAD + r];          // ds_read_b32, banks spread
            const float sb = Sl[SHALF + k * SPAD + r];
            const float h2 = fmaxf(fmaf(xv, sw, sb), 0.0f);
            const float* w3r = w3 + k * NH3;            // wave-uniform -> s_load
            G0  = fma2s(h2, ld2(w3r +  0), G0);  G1  = fma2s(h2, ld2(w3r +  2), G1);
            G2  = fma2s(h2, ld2(w3r +  4), G2);  G3  = fma2s(h2, ld2(w3r +  6), G3);
            G4  = fma2s(h2, ld2(w3r +  8), G4);  G5  = fma2s(h2, ld2(w3r + 10), G5);
            G6  = fma2s(h2, ld2(w3r + 12), G6);  G7  = fma2s(h2, ld2(w3r + 14), G7);
            G8  = fma2s(h2, ld2(w3r + 16), G8);  G9  = fma2s(h2, ld2(w3r + 18), G9);
            G10 = fma2s(h2, ld2(w3r + 20), G10); G11 = fma2s(h2, ld2(w3r + 22), G11);
            G12 = fma2s(h2, ld2(w3r + 24), G12); G13 = fma2s(h2, ld2(w3r + 26), G13);
            G14 = fma2s(h2, ld2(w3r + 28), G14); G15 = fma2s(h2, ld2(w3r + 30), G15);
        }

        // layer 4
        fvec2 OV = {0.0f, 0.0f};
        OV = __builtin_elementwise_fma(relu2(G0),  ld2(w4 + 0),  OV);
        OV = __builtin_elementwise_fma(relu2(G1),  ld2(w4 + 2),  OV);
        OV = __builtin_elementwise_fma(relu2(G2),  ld2(w4 + 4),  OV);
        OV = __builtin_elementwise_fma(relu2(G3),  ld2(w4 + 6),  OV);
        OV = __builtin_elementwise_fma(relu2(G4),  ld2(w4 + 8),  OV);
        OV = __builtin_elementwise_fma(relu2(G5),  ld2(w4 + 10), OV);
        OV = __builtin_elementwise_fma(relu2(G6),  ld2(w4 + 12), OV);
        OV = __builtin_elementwise_fma(relu2(G7),  ld2(w4 + 14), OV);
        OV = __builtin_elementwise_fma(relu2(G8),  ld2(w4 + 16), OV);
        OV = __builtin_elementwise_fma(relu2(G9),  ld2(w4 + 18), OV);
        OV = __builtin_elementwise_fma(relu2(G10), ld2(w4 + 20), OV);
        OV = __builtin_elementwise_fma(relu2(G11), ld2(w4 + 22), OV);
        OV = __builtin_elementwise_fma(relu2(G12), ld2(w4 + 24), OV);
        OV = __builtin_elementwise_fma(relu2(G13), ld2(w4 + 26), OV);
        OV = __builtin_elementwise_fma(relu2(G14), ld2(w4 + 28), OV);
        OV = __builtin_elementwise_fma(relu2(G15), ld2(w4 + 30), OV);
        const float o = b4f + (OV.x + OV.y);

        atomicAdd(&out[b], o);
    }
}

extern "C" void kernel_launch(void* const* d_in, const int* in_sizes, int n_in,
                              void* d_out, int out_size, void* d_ws, size_t ws_size,
                              hipStream_t stream) {
    const float* x    = (const float*)d_in[0];
    const float* W1   = (const float*)d_in[1];
    const float* b1   = (const float*)d_in[2];
    const float* W2   = (const float*)d_in[3];
    const float* b2   = (const float*)d_in[4];
    const float* W3   = (const float*)d_in[5];
    const float* b3   = (const float*)d_in[6];
    const float* W4   = (const float*)d_in[7];
    const float* b4   = (const float*)d_in[8];
    const float* bias = (const float*)d_in[9];
    float* out = (float*)d_out;
    float* ws  = (float*)d_ws;   // needs 256*FSTRIDE*4 = 17.4 MB

    init_out_kernel<<<NB / 256, 256, 0, stream>>>(out, bias);
    build_tables<<<NF, 64, 0, stream>>>(W1, b1, W2, b2, ws);
    nam_main<<<NF * 4, 1024, 0, stream>>>(x, W3, b3, W4, b4, ws, out);
}

// Round 8
// 199.094 us; speedup vs baseline: 3.0838x; 1.0540x over previous
//
#include <hip/hip_runtime.h>
#include <math.h>

// Neural Additive Model: 256 per-feature MLPs 1->128->64->32->1 (ReLU), summed.
// B=8192, fp32.
//
// Exact rank-table decomposition (round 5): pre-relu h2[b,k] = x_b*Sw[r,k] + Sb[r,k],
// r = #(sorted layer-1 thresholds < x_b). Layers 2-relu/3/4 explicit.
//
// Round 8: FIX round-7 correctness bug — the chunked prefix scan dropped the
// layer-2 bias b2 from the table base (round 6 seeded accb with b2; round 7's
// per-chunk partials started at 0). One line: seed the start accumulator.
// Perf structure unchanged from round 7:
//  * (Sw,Sb) packed float2 -> ONE ds_read_b64 per k (conflicts are balls-in-bins
//    from random ranks; halving LDS instruction count halves conflict cycles).
//  * grid 256 = 1 feature/block, 8 elems/thread: table staged once, 1 block/CU.
//  * x transposed first (coalesced main-kernel loads); runtime ws_size fallback.
//  * build_tables: 4-chunk parallel prefix scan + coalesced float4 output.

typedef float fvec2 __attribute__((ext_vector_type(2)));

#define NF   256
#define NH1  128
#define NH2  64
#define NH3  32
#define NB   8192

#define SPAD2 130                        // float2 stride per k-row (even -> f4 ok)
// floats per feature table: T[128] + SP[64*130] float2
#define TBLF (NH1 + NH2 * SPAD2 * 2)     // 16768 floats = 67072 B

__device__ __forceinline__ fvec2 ld2(const float* p) { return *(const fvec2*)p; }
__device__ __forceinline__ fvec2 relu2(fvec2 v) {
    fvec2 z = {0.0f, 0.0f};
    return __builtin_elementwise_max(v, z);
}
__device__ __forceinline__ fvec2 fma2s(float a, fvec2 b, fvec2 c) {
    fvec2 av; av.x = a; av.y = a;
    return __builtin_elementwise_fma(av, b, c);
}

__global__ __launch_bounds__(256) void init_out_kernel(float* __restrict__ out,
                                                       const float* __restrict__ bias) {
    int i = blockIdx.x * 256 + threadIdx.x;
    if (i < NB) out[i] = bias[0];
}

// ---------------- x transpose: x[b][f] -> xT[f][b], 64x64 LDS tiles ----------------
__global__ __launch_bounds__(256) void transpose_x(const float* __restrict__ x,
                                                   float* __restrict__ xT) {
    __shared__ float tile[64][65];
    const int bf = blockIdx.x & 3;          // f tile (256/64)
    const int bb = blockIdx.x >> 2;         // b tile (8192/64)
    const int tx = threadIdx.x & 63, ty = threadIdx.x >> 6;
    const int f0 = bf * 64, b0 = bb * 64;
    #pragma unroll
    for (int i = 0; i < 16; ++i) {
        int row = i * 4 + ty;
        tile[row][tx] = x[(size_t)(b0 + row) * NF + f0 + tx];   // coalesced read
    }
    __syncthreads();
    #pragma unroll
    for (int i = 0; i < 16; ++i) {
        int row = i * 4 + ty;
        xT[(size_t)(f0 + row) * NB + b0 + tx] = tile[tx][row];  // coalesced write
    }
}

// ---------------- table build: one block (256 threads) per feature ----------------
__global__ __launch_bounds__(256) void build_tables(
    const float* __restrict__ W1, const float* __restrict__ b1,
    const float* __restrict__ W2, const float* __restrict__ b2,
    float* __restrict__ ws)
{
    __shared__ float  w2s[NH1 * NH2];      // 32 KB
    __shared__ float2 SP[NH2 * SPAD2];     // 66.6 KB (Sw,Sb) k-major
    __shared__ float  tkey[NH1];
    __shared__ int    tidx[NH1];
    __shared__ float  w1s[NH1], b1s[NH1];
    __shared__ float  DwS[NH2 * 4], DbS[NH2 * 4], BwS[NH2 * 4], BbS[NH2 * 4];

    const int f = blockIdx.x;
    const int t = (int)threadIdx.x;

    // stage W2[f] (32 KB), W1/b1, threshold keys
    {
        const float4* w2g = (const float4*)(W2 + (size_t)f * NH1 * NH2);
        float4* w2l = (float4*)w2s;
        #pragma unroll 2
        for (int i = t; i < NH1 * NH2 / 4; i += 256) w2l[i] = w2g[i];
    }
    if (t < NH1) {
        float w  = W1[f * NH1 + t];
        float bb = b1[f * NH1 + t];
        w1s[t] = w; b1s[t] = bb;
        tkey[t] = (w != 0.0f) ? (-bb / w) : INFINITY;   // w==0: never toggled
        tidx[t] = t;
    }
    __syncthreads();

    // bitonic sort of 128 (key asc, payload idx); wave 0 does the work
    for (int size = 2; size <= NH1; size <<= 1) {
        for (int stride = size >> 1; stride > 0; stride >>= 1) {
            if (t < 64) {
                int pos = ((t / stride) * (stride << 1)) + (t % stride);
                int par = pos + stride;
                bool up = ((pos & size) == 0);
                float a = tkey[pos], c = tkey[par];
                int  ia = tidx[pos], ic = tidx[par];
                if ((a > c) == up) {
                    tkey[pos] = c; tkey[par] = a;
                    tidx[pos] = ic; tidx[par] = ia;
                }
            }
            __syncthreads();
        }
    }

    // chunked scan: thread = (k = t>>2, c = t&3); each chunk covers 32 j / 32 ranks
    const int k = t >> 2, c = t & 3;

    // partial rank-0 base over j in [c*32, c*32+32):
    //   w<0 active; w==0 && b>0 constant-on
    float bw = 0.0f, bbp = 0.0f;
    #pragma unroll 4
    for (int i = 0; i < 32; ++i) {
        int j = c * 32 + i;
        float w = w1s[j], bv = b1s[j], w2v = w2s[j * NH2 + k];
        if (w < 0.0f) { bw = fmaf(w, w2v, bw); bbp = fmaf(bv, w2v, bbp); }
        else if (w == 0.0f && bv > 0.0f) { bbp = fmaf(bv, w2v, bbp); }
    }
    // partial toggle deltas over ranks r in [c*32, c*32+32)
    float dw = 0.0f, db = 0.0f;
    #pragma unroll 4
    for (int i = 0; i < 32; ++i) {
        int r = c * 32 + i;
        int j = tidx[r];
        float w = w1s[j], bv = b1s[j], w2v = w2s[j * NH2 + k];
        float s = (w > 0.0f) ? 1.0f : ((w < 0.0f) ? -1.0f : 0.0f);
        dw = fmaf(s * w,  w2v, dw);
        db = fmaf(s * bv, w2v, db);
    }
    DwS[k * 4 + c] = dw; DbS[k * 4 + c] = db;
    BwS[k * 4 + c] = bw; BbS[k * 4 + c] = bbp;
    __syncthreads();

    // start accumulator = b2 (ROUND-8 FIX: was dropped in round 7)
    //                     + full rank-0 base + deltas of preceding chunks
    float accw = BwS[k * 4 + 0] + BwS[k * 4 + 1] + BwS[k * 4 + 2] + BwS[k * 4 + 3];
    float accb = b2[f * NH2 + k]
               + BbS[k * 4 + 0] + BbS[k * 4 + 1] + BbS[k * 4 + 2] + BbS[k * 4 + 3];
    for (int c2 = 0; c2 < c; ++c2) { accw += DwS[k * 4 + c2]; accb += DbS[k * 4 + c2]; }
    if (c == 0) { float2 v; v.x = accw; v.y = accb; SP[k * SPAD2] = v; }
    // walk 32 ranks, emit S[r+1]
    #pragma unroll 4
    for (int i = 0; i < 32; ++i) {
        int r = c * 32 + i;
        int j = tidx[r];
        float w = w1s[j], bv = b1s[j], w2v = w2s[j * NH2 + k];
        float s = (w > 0.0f) ? 1.0f : ((w < 0.0f) ? -1.0f : 0.0f);
        accw = fmaf(s * w,  w2v, accw);
        accb = fmaf(s * bv, w2v, accb);
        float2 v; v.x = accw; v.y = accb;
        SP[k * SPAD2 + r + 1] = v;
    }
    __syncthreads();

    // coalesced copy-out: T[128] then SP flat
    float* tg = ws + (size_t)f * TBLF;
    if (t < NH1) tg[t] = tkey[t];
    const float4* src = (const float4*)SP;
    float4* dst = (float4*)(tg + NH1);
    #pragma unroll 2
    for (int i = t; i < NH2 * SPAD2 / 2; i += 256) dst[i] = src[i];
}

// ---------------- main: one block = one feature, 8 elems/thread ----------------
template <bool USE_XT>
__global__ __launch_bounds__(1024, 4) void nam_main(
    const float* __restrict__ x,      // [B][F] (fallback)
    const float* __restrict__ xT,     // [F][B] (preferred)
    const float* __restrict__ W3, const float* __restrict__ b3,
    const float* __restrict__ W4, const float* __restrict__ b4,
    const float* __restrict__ ws,
    float* __restrict__ out)
{
    __shared__ float2 SP[NH2 * SPAD2];   // 66.6 KB (Sw,Sb) k-major
    __shared__ float  Tl[NH1];

    const int f = blockIdx.x;            // feature (wave-uniform)
    const int t = (int)threadIdx.x;

    // stage table (flat layout identical to global)
    {
        const float* tg = ws + (size_t)f * TBLF;
        const float4* src = (const float4*)(tg + NH1);
        float4* dst = (float4*)SP;
        #pragma unroll 2
        for (int i = t; i < NH2 * SPAD2 / 2; i += 1024) dst[i] = src[i];
        if (t < NH1) Tl[t] = tg[t];
    }
    __syncthreads();

    const float* __restrict__ w3  = W3 + f * NH2 * NH3;
    const float* __restrict__ bb3 = b3 + f * NH3;
    const float* __restrict__ w4  = W4 + f * NH3;
    const float b4f = b4[f];
    const float* __restrict__ xcol = xT + (size_t)f * NB;

    #pragma unroll 1
    for (int e = 0; e < 8; ++e) {
        const int b = e * 1024 + t;
        const float xv = USE_XT ? xcol[b] : x[(size_t)b * NF + f];

        // rank = #(T < xv), branchless binary search
        int r = 0;
        #pragma unroll
        for (int s = 64; s > 0; s >>= 1)
            if (Tl[r + s - 1] < xv) r += s;

        // h3 accumulators (32 floats), init b3
        fvec2 G0 = ld2(bb3 + 0),  G1 = ld2(bb3 + 2),  G2 = ld2(bb3 + 4),  G3 = ld2(bb3 + 6),
              G4 = ld2(bb3 + 8),  G5 = ld2(bb3 + 10), G6 = ld2(bb3 + 12), G7 = ld2(bb3 + 14),
              G8 = ld2(bb3 + 16), G9 = ld2(bb3 + 18), G10 = ld2(bb3 + 20), G11 = ld2(bb3 + 22),
              G12 = ld2(bb3 + 24), G13 = ld2(bb3 + 26), G14 = ld2(bb3 + 28), G15 = ld2(bb3 + 30);

        // layer 2(table lookup)+relu, then layer 3
        #pragma unroll 2
        for (int k = 0; k < NH2; ++k) {
            const float2 sv = SP[k * SPAD2 + r];        // one ds_read_b64
            const float h2 = fmaxf(fmaf(xv, sv.x, sv.y), 0.0f);
            const float* w3r = w3 + k * NH3;            // wave-uniform -> s_load
            G0  = fma2s(h2, ld2(w3r +  0), G0);  G1  = fma2s(h2, ld2(w3r +  2), G1);
            G2  = fma2s(h2, ld2(w3r +  4), G2);  G3  = fma2s(h2, ld2(w3r +  6), G3);
            G4  = fma2s(h2, ld2(w3r +  8), G4);  G5  = fma2s(h2, ld2(w3r + 10), G5);
            G6  = fma2s(h2, ld2(w3r + 12), G6);  G7  = fma2s(h2, ld2(w3r + 14), G7);
            G8  = fma2s(h2, ld2(w3r + 16), G8);  G9  = fma2s(h2, ld2(w3r + 18), G9);
            G10 = fma2s(h2, ld2(w3r + 20), G10); G11 = fma2s(h2, ld2(w3r + 22), G11);
            G12 = fma2s(h2, ld2(w3r + 24), G12); G13 = fma2s(h2, ld2(w3r + 26), G13);
            G14 = fma2s(h2, ld2(w3r + 28), G14); G15 = fma2s(h2, ld2(w3r + 30), G15);
        }

        // layer 4
        fvec2 OV = {0.0f, 0.0f};
        OV = __builtin_elementwise_fma(relu2(G0),  ld2(w4 + 0),  OV);
        OV = __builtin_elementwise_fma(relu2(G1),  ld2(w4 + 2),  OV);
        OV = __builtin_elementwise_fma(relu2(G2),  ld2(w4 + 4),  OV);
        OV = __builtin_elementwise_fma(relu2(G3),  ld2(w4 + 6),  OV);
        OV = __builtin_elementwise_fma(relu2(G4),  ld2(w4 + 8),  OV);
        OV = __builtin_elementwise_fma(relu2(G5),  ld2(w4 + 10), OV);
        OV = __builtin_elementwise_fma(relu2(G6),  ld2(w4 + 12), OV);
        OV = __builtin_elementwise_fma(relu2(G7),  ld2(w4 + 14), OV);
        OV = __builtin_elementwise_fma(relu2(G8),  ld2(w4 + 16), OV);
        OV = __builtin_elementwise_fma(relu2(G9),  ld2(w4 + 18), OV);
        OV = __builtin_elementwise_fma(relu2(G10), ld2(w4 + 20), OV);
        OV = __builtin_elementwise_fma(relu2(G11), ld2(w4 + 22), OV);
        OV = __builtin_elementwise_fma(relu2(G12), ld2(w4 + 24), OV);
        OV = __builtin_elementwise_fma(relu2(G13), ld2(w4 + 26), OV);
        OV = __builtin_elementwise_fma(relu2(G14), ld2(w4 + 28), OV);
        OV = __builtin_elementwise_fma(relu2(G15), ld2(w4 + 30), OV);
        const float o = b4f + (OV.x + OV.y);

        atomicAdd(&out[b], o);
    }
}

extern "C" void kernel_launch(void* const* d_in, const int* in_sizes, int n_in,
                              void* d_out, int out_size, void* d_ws, size_t ws_size,
                              hipStream_t stream) {
    const float* x    = (const float*)d_in[0];
    const float* W1   = (const float*)d_in[1];
    const float* b1   = (const float*)d_in[2];
    const float* W2   = (const float*)d_in[3];
    const float* b2   = (const float*)d_in[4];
    const float* W3   = (const float*)d_in[5];
    const float* b3   = (const float*)d_in[6];
    const float* W4   = (const float*)d_in[7];
    const float* b4   = (const float*)d_in[8];
    const float* bias = (const float*)d_in[9];
    float* out = (float*)d_out;
    float* ws  = (float*)d_ws;

    const size_t tbl_bytes = (size_t)NF * TBLF * sizeof(float);        // 17.2 MB
    const size_t xt_bytes  = (size_t)NB * NF * sizeof(float);          //  8.4 MB
    const bool use_xt = (ws_size >= tbl_bytes + xt_bytes);             // constant per run
    float* xT = ws + (size_t)NF * TBLF;

    init_out_kernel<<<NB / 256, 256, 0, stream>>>(out, bias);
    build_tables<<<NF, 256, 0, stream>>>(W1, b1, W2, b2, ws);
    if (use_xt) {
        transpose_x<<<(NB / 64) * (NF / 64), 256, 0, stream>>>(x, xT);
        nam_main<true><<<NF, 1024, 0, stream>>>(x, xT, W3, b3, W4, b4, ws, out);
    } else {
        nam_main<false><<<NF, 1024, 0, stream>>>(x, xT, W3, b3, W4, b4, ws, out);
    }
}